// Round 1
// baseline (670.764 us; speedup 1.0000x reference)
//
#include <hip/hip_runtime.h>

// FractalDimension: out[row] = sum_{l=0}^{1023} in[row*1024 + l] / (l+1)
// rows = C*B*N = 131072, L = 1024, fp32 in/out.
// Memory-bound: 512 MiB read @ ~6.3 TB/s -> ~85 us floor for the compute kernel.
//
// Structure: persistent waves. 2048 blocks x 256 threads = 8192 waves,
// one wave per row, grid-stride (16 rows/wave), 2 rows per iteration for ILP.
// Reciprocals 1/(l+1) depend only on lane position within the row -> computed
// once per wave with exact divides (amortized over 16 rows), then pure fma.
// No __syncthreads, no LDS, no per-row divide sequences.

constexpr int kL = 1024;

__global__ __launch_bounds__(256) void FractalDimension_kernel(
    const float* __restrict__ in, float* __restrict__ out, int rows) {
  const int lane = threadIdx.x & 63;
  const int gwave = (int)((blockIdx.x * blockDim.x + threadIdx.x) >> 6);
  const int nwaves = (int)((gridDim.x * blockDim.x) >> 6);

  // Element index for (it, j): it*256 + lane*4 + j ; coefficient = 1/(idx+1).
  // Exact IEEE divides, paid once per wave (~16 rows amortization).
  float r[4][4];
#pragma unroll
  for (int it = 0; it < 4; ++it) {
#pragma unroll
    for (int j = 0; j < 4; ++j) {
      r[it][j] = 1.0f / (float)(it * 256 + lane * 4 + j + 1);
    }
  }

  // Each wave owns row pairs: {2w, 2w+1}, {2w+2*nwaves, ...}, stride 2*nwaves.
  for (int row = gwave * 2; row < rows; row += 2 * nwaves) {
    const bool has2 = (row + 1) < rows;
    const float4* p0 =
        reinterpret_cast<const float4*>(in + (size_t)row * kL) + lane;
    const float4* p1 = p0 + (kL / 4);  // next row

    float s0 = 0.0f, s1 = 0.0f;
#pragma unroll
    for (int it = 0; it < 4; ++it) {
      float4 v0 = p0[it * 64];
      s0 = fmaf(v0.x, r[it][0], s0);
      s0 = fmaf(v0.y, r[it][1], s0);
      s0 = fmaf(v0.z, r[it][2], s0);
      s0 = fmaf(v0.w, r[it][3], s0);
      if (has2) {
        float4 v1 = p1[it * 64];
        s1 = fmaf(v1.x, r[it][0], s1);
        s1 = fmaf(v1.y, r[it][1], s1);
        s1 = fmaf(v1.z, r[it][2], s1);
        s1 = fmaf(v1.w, r[it][3], s1);
      }
    }

    // Two independent butterfly reduces; scheduler interleaves the chains.
#pragma unroll
    for (int off = 32; off > 0; off >>= 1) {
      s0 += __shfl_down(s0, off, 64);
      s1 += __shfl_down(s1, off, 64);
    }

    if (lane == 0) {
      out[row] = s0;
      if (has2) out[row + 1] = s1;
    }
  }
}

extern "C" void kernel_launch(void* const* d_in, const int* in_sizes, int n_in,
                              void* d_out, int out_size, void* d_ws,
                              size_t ws_size, hipStream_t stream) {
  const float* in = (const float*)d_in[0];
  float* out = (float*)d_out;
  const int rows = in_sizes[0] / kL;  // 131072
  // 2048 blocks = 8 blocks/CU on 256 CUs -> full occupancy, persistent waves.
  FractalDimension_kernel<<<2048, 256, 0, stream>>>(in, out, rows);
}

// Round 3
// 652.481 us; speedup vs baseline: 1.0280x; 1.0280x over previous
//
#include <hip/hip_runtime.h>

// FractalDimension: out[row] = sum_{l=0}^{1023} in[row*1024 + l] / (l+1)
// rows = C*B*N = 131072, L = 1024, fp32 in/out.
// Memory-bound: 512 MiB read @ ~6.3 TB/s -> ~85 us floor for the compute kernel.
//
// Persistent waves: 2048 blocks x 256 threads = 8192 waves (8 blocks/CU,
// 32 waves/CU = max TLP). One wave per row per iteration, grid-stride
// (16 rows/wave). Reciprocals 1/(l+1) depend only on lane position ->
// computed once per wave in SIXTEEN EXPLICIT SCALARS (an indexed float[4][4]
// risks scratch allocation — rule #20). Loads are batched nontemporal
// dwordx4 via clang ext_vector_type (read-once stream, don't pollute L2/L3;
// __builtin_nontemporal_load rejects HIP_vector_type — needs ext_vector).

constexpr int kL = 1024;

typedef float f32x4 __attribute__((ext_vector_type(4)));

__global__ __launch_bounds__(256) void FractalDimension_kernel(
    const float* __restrict__ in, float* __restrict__ out, int rows) {
  const int lane = threadIdx.x & 63;
  const int gwave = (int)((blockIdx.x * blockDim.x + threadIdx.x) >> 6);
  const int nwaves = (int)((gridDim.x * blockDim.x) >> 6);

  // Element index for (it, j): it*256 + lane*4 + j ; coefficient = 1/(idx+1).
  // Exact IEEE divides, paid once per wave, amortized over 16 rows.
  const float b = (float)(lane * 4 + 1);
  const float r00 = 1.0f / (b + 0.0f),   r01 = 1.0f / (b + 1.0f);
  const float r02 = 1.0f / (b + 2.0f),   r03 = 1.0f / (b + 3.0f);
  const float r10 = 1.0f / (b + 256.0f), r11 = 1.0f / (b + 257.0f);
  const float r12 = 1.0f / (b + 258.0f), r13 = 1.0f / (b + 259.0f);
  const float r20 = 1.0f / (b + 512.0f), r21 = 1.0f / (b + 513.0f);
  const float r22 = 1.0f / (b + 514.0f), r23 = 1.0f / (b + 515.0f);
  const float r30 = 1.0f / (b + 768.0f), r31 = 1.0f / (b + 769.0f);
  const float r32 = 1.0f / (b + 770.0f), r33 = 1.0f / (b + 771.0f);

  for (int row = gwave; row < rows; row += nwaves) {
    const f32x4* p =
        reinterpret_cast<const f32x4*>(in + (size_t)row * kL) + lane;

    // All four loads issued back-to-back -> one vmcnt wait, then pure math.
    f32x4 v0 = __builtin_nontemporal_load(p);
    f32x4 v1 = __builtin_nontemporal_load(p + 64);
    f32x4 v2 = __builtin_nontemporal_load(p + 128);
    f32x4 v3 = __builtin_nontemporal_load(p + 192);

    // Four independent accumulator chains, pairwise combine.
    float a0 = v0.x * r00, a1 = v1.x * r10, a2 = v2.x * r20, a3 = v3.x * r30;
    a0 = fmaf(v0.y, r01, a0);
    a1 = fmaf(v1.y, r11, a1);
    a2 = fmaf(v2.y, r21, a2);
    a3 = fmaf(v3.y, r31, a3);
    a0 = fmaf(v0.z, r02, a0);
    a1 = fmaf(v1.z, r12, a1);
    a2 = fmaf(v2.z, r22, a2);
    a3 = fmaf(v3.z, r32, a3);
    a0 = fmaf(v0.w, r03, a0);
    a1 = fmaf(v1.w, r13, a1);
    a2 = fmaf(v2.w, r23, a2);
    a3 = fmaf(v3.w, r33, a3);
    float s = (a0 + a1) + (a2 + a3);

    // Wave-64 butterfly reduce.
#pragma unroll
    for (int off = 32; off > 0; off >>= 1) s += __shfl_down(s, off, 64);

    if (lane == 0) out[row] = s;
  }
}

extern "C" void kernel_launch(void* const* d_in, const int* in_sizes, int n_in,
                              void* d_out, int out_size, void* d_ws,
                              size_t ws_size, hipStream_t stream) {
  const float* in = (const float*)d_in[0];
  float* out = (float*)d_out;
  const int rows = in_sizes[0] / kL;  // 131072
  FractalDimension_kernel<<<2048, 256, 0, stream>>>(in, out, rows);
}